// Round 8
// baseline (368.013 us; speedup 1.0000x reference)
//
#include <hip/hip_runtime.h>
#include <math.h>

typedef __bf16 bf16_t;
typedef unsigned char u8;
typedef long i64;
typedef __attribute__((ext_vector_type(8))) __bf16 bf16x8;
typedef __attribute__((ext_vector_type(4))) __bf16 bf16x4;
typedef __attribute__((ext_vector_type(4))) float f32x4;
typedef __attribute__((ext_vector_type(4))) int i32x4;
typedef __attribute__((ext_vector_type(8))) int i32x8;

#define AS_GLOBAL __attribute__((address_space(1)))
#define AS_LDS    __attribute__((address_space(3)))

__device__ __forceinline__ void async_copy16(const void* g, void* l) {
  __builtin_amdgcn_global_load_lds((const AS_GLOBAL void*)g, (AS_LDS void*)l, 16, 0, 0);
}

__device__ __forceinline__ u8 to_fp8(float v) {
  return (u8)(__builtin_amdgcn_cvt_pk_fp8_f32(v, v, 0, false) & 0xff);
}

struct CastArgs {
  const float* s[8];
  u8* d[8];
  int n[8];
};

// fp32 -> fp8 cast, 8 elems/thread; blockIdx.y selects tensor.
__global__ __launch_bounds__(256) void cast_f32_fp8_8(CastArgs a) {
  const int y = blockIdx.y;
  const float* s = a.s[y];
  u8* d = a.d[y];
  const int n = a.n[y];
  int i = (blockIdx.x * 256 + threadIdx.x) * 8;
  if (i >= n) return;
  float4 v0 = *(const float4*)(s + i);
  float4 v1 = *(const float4*)(s + i + 4);
  int w0 = __builtin_amdgcn_cvt_pk_fp8_f32(v0.x, v0.y, 0, false);
  w0 = __builtin_amdgcn_cvt_pk_fp8_f32(v0.z, v0.w, w0, true);
  int w1 = __builtin_amdgcn_cvt_pk_fp8_f32(v1.x, v1.y, 0, false);
  w1 = __builtin_amdgcn_cvt_pk_fp8_f32(v1.z, v1.w, w1, true);
  int2 o; o.x = w0; o.y = w1;
  *(int2*)(d + i) = o;
}

// 2-way fp32->bf16 cast (output-linear weights stay bf16 for precision).
__global__ __launch_bounds__(256) void cast_f32_bf16_2(
    const float* __restrict__ s0, const float* __restrict__ s1,
    bf16_t* __restrict__ d0, bf16_t* __restrict__ d1, int n) {
  const float* s = blockIdx.y ? s1 : s0;
  bf16_t* d = blockIdx.y ? d1 : d0;
  int i = (blockIdx.x * 256 + threadIdx.x) * 4;
  if (i >= n) return;
  float4 v = *(const float4*)(s + i);
  bf16x4 o;
  o[0] = (bf16_t)v.x; o[1] = (bf16_t)v.y; o[2] = (bf16_t)v.z; o[3] = (bf16_t)v.w;
  *(bf16x4*)(d + i) = o;
}

// ---------------- fp8 GEMM: C = A[M x K] @ B[N x K]^T, both dirs batched ----
// 128x128 tile, BK=128, mfma_scale 16x16x128 f8f6f4 (scale=1.0 exact; 2x rate
// of non-scaled fp8 [m148 vs m145]), fragments via 2x ds_read_b128 (16B reads
// = conflict-free with the 16B XOR swizzle; the former ds_read_b64 pattern
// was a structural 4-way conflict, 8.4M cycles in R7).
// z-decode: MODE 2: dir=z.  MODE 0/1: dir=z>>3, head=z&7.
// MODE 0 (QK):  S8 = fp8(exp(acc*scale)); fp32 rowsums -> partial[z][bx][2048]
// MODE 1 (PV):  bf16 C = acc / (sum_{b<16} partial[z][b][row])
// MODE 2 (proj): A-switch at n0 (Xq for cols<4096, Xkv beyond); fp8 outputs:
//   cols [0,4096):     q8 [dir][row][c]          = fp8(acc + bq[c])
//   cols [4096,8192):  K8 [dir][row][c-4096]     = fp8(acc + bk[..])
//   cols [8192,12288): V8 [dir][(c-8192)][row]   = fp8(acc + bv[..])  (V^T)
template <int MODE>
__global__ __launch_bounds__(256, 2) void gemm_f8(
    const u8* __restrict__ A, const u8* __restrict__ A2, int lda, long aDir, long aHead,
    const u8* __restrict__ B, int ldb, long bDir, long bHead,
    void* __restrict__ Cv, int ldc, long cDir, long cHead,
    u8* __restrict__ K8, u8* __restrict__ V8,
    float* __restrict__ partial,
    const float* __restrict__ bq0, const float* __restrict__ bk0, const float* __restrict__ bv0,
    const float* __restrict__ bq1, const float* __restrict__ bk1, const float* __restrict__ bv1,
    float scale, int K)
{
  __shared__ __align__(16) u8 lds_a[128 * 128];
  __shared__ __align__(16) u8 lds_b[128 * 128];

  const int tid = threadIdx.x;
  const int lane = tid & 63;
  const int wid = tid >> 6;
  const int wm = (wid >> 1) * 64;
  const int wn = (wid & 1) * 64;
  const int m0 = blockIdx.y * 128;
  const int n0 = blockIdx.x * 128;
  const int z = blockIdx.z;
  const int dir = (MODE == 2) ? z : (z >> 3);
  const int head = (MODE == 2) ? 0 : (z & 7);

  const u8* Ap;
  if (MODE == 2) {
    const u8* Aq  = dir ? A : A2;    // A=img8, A2=meta8; dir0 queries=metadata
    const u8* Akv = dir ? A2 : A;
    Ap = (n0 < 4096) ? Aq : Akv;
  } else {
    Ap = A + (long)dir * aDir + (long)head * aHead;
  }
  const u8* Bp = B + (long)dir * bDir + (long)head * bHead;
  const long cOff = (long)dir * cDir + (long)head * cHead;
  u8*     C8 = (u8*)Cv + cOff;
  bf16_t* Cb = (bf16_t*)Cv + cOff;

  // 1024 16B segments per 128x128B tile; 4/thread; XOR swizzle phys=ks^(row&7)
  const u8* gA[4];
  const u8* gB[4];
  int ldsOff[4];
#pragma unroll
  for (int j = 0; j < 4; ++j) {
    int p = j * 256 + tid;
    int row = p >> 3;
    int ksl = (p & 7) ^ (row & 7);
    ldsOff[j] = p * 16;
    gA[j] = Ap + (long)(m0 + row) * lda + ksl * 16;
    gB[j] = Bp + (long)(n0 + row) * ldb + ksl * 16;
  }

  f32x4 acc[4][4];
#pragma unroll
  for (int i = 0; i < 4; ++i)
#pragma unroll
    for (int j = 0; j < 4; ++j) acc[i][j] = f32x4{0.f, 0.f, 0.f, 0.f};

  const int q = lane >> 4;
  const int r16 = lane & 15;

  for (int kt = 0; kt < K; kt += 128) {
#pragma unroll
    for (int j = 0; j < 4; ++j) {
      async_copy16(gA[j] + kt, &lds_a[ldsOff[j]]);
      async_copy16(gB[j] + kt, &lds_b[ldsOff[j]]);
    }
    __syncthreads();
    // lane (r16, quad q) holds k-bytes [q*32, q*32+32) = logical segs {2q,2q+1};
    // identical A/B load patterns make the result invariant to the HW k-mapping.
    i32x8 af[4], bfr[4];
#pragma unroll
    for (int i = 0; i < 4; ++i) {
      int ra = wm + i * 16 + r16;
      int pa = ((2 * q) ^ (ra & 7)) * 16;
      i32x4 alo = *(const i32x4*)&lds_a[ra * 128 + pa];
      i32x4 ahi = *(const i32x4*)&lds_a[ra * 128 + (pa ^ 16)];
      int rb = wn + i * 16 + r16;
      int pb = ((2 * q) ^ (rb & 7)) * 16;
      i32x4 blo = *(const i32x4*)&lds_b[rb * 128 + pb];
      i32x4 bhi = *(const i32x4*)&lds_b[rb * 128 + (pb ^ 16)];
#pragma unroll
      for (int t = 0; t < 4; ++t) {
        af[i][t] = alo[t]; af[i][4 + t] = ahi[t];
        bfr[i][t] = blo[t]; bfr[i][4 + t] = bhi[t];
      }
    }
#pragma unroll
    for (int i = 0; i < 4; ++i)
#pragma unroll
      for (int j = 0; j < 4; ++j)
        acc[i][j] = __builtin_amdgcn_mfma_scale_f32_16x16x128_f8f6f4(
            af[i], bfr[j], acc[i][j], 0, 0, 0, 127, 0, 127);  // fp8/fp8, scale=1.0
    __syncthreads();
  }

  // C/D layout: col=lane&15, row=(lane>>4)*4+reg  [m89-verified, shape-determined]
  if (MODE == 0) {   // QK
    float rowsum[4][4];
#pragma unroll
    for (int i = 0; i < 4; ++i)
#pragma unroll
      for (int r = 0; r < 4; ++r) rowsum[i][r] = 0.f;
#pragma unroll
    for (int i = 0; i < 4; ++i) {
      const int row0 = m0 + wm + i * 16 + q * 4;
#pragma unroll
      for (int j = 0; j < 4; ++j) {
        const int colg = n0 + wn + j * 16 + r16;
#pragma unroll
        for (int r = 0; r < 4; ++r) {
          float pv = __expf(acc[i][j][r] * scale);
          C8[(long)(row0 + r) * ldc + colg] = to_fp8(pv);
          rowsum[i][r] += pv;
        }
      }
    }
#pragma unroll
    for (int m = 1; m <= 8; m <<= 1)
#pragma unroll
      for (int i = 0; i < 4; ++i)
#pragma unroll
        for (int r = 0; r < 4; ++r)
          rowsum[i][r] += __shfl_xor(rowsum[i][r], m, 64);
    float* lsum = (float*)lds_a;   // safe: loop-end barrier drained all reads
    if (r16 == 0) {
#pragma unroll
      for (int i = 0; i < 4; ++i)
#pragma unroll
        for (int r = 0; r < 4; ++r)
          lsum[(wm + i * 16 + q * 4 + r) * 2 + (wid & 1)] = rowsum[i][r];
    }
    __syncthreads();
    if (tid < 128) {
      float s = lsum[tid * 2] + lsum[tid * 2 + 1];
      partial[((long)z * gridDim.x + blockIdx.x) * 2048 + m0 + tid] = s;
    }
  } else if (MODE == 1) {   // PV: normalize by rowsum
#pragma unroll
    for (int i = 0; i < 4; ++i) {
      const int row0 = m0 + wm + i * 16 + q * 4;
      float w[4];
#pragma unroll
      for (int r = 0; r < 4; ++r) {
        const float* pp = partial + (long)z * 16 * 2048 + row0 + r;
        float s = 0.f;
#pragma unroll
        for (int b = 0; b < 16; ++b) s += pp[b * 2048];
        w[r] = 1.f / s;
      }
#pragma unroll
      for (int j = 0; j < 4; ++j) {
        const int colg = n0 + wn + j * 16 + r16;
#pragma unroll
        for (int r = 0; r < 4; ++r)
          Cb[(long)(row0 + r) * ldc + colg] = (bf16_t)(acc[i][j][r] * w[r]);
      }
    }
  } else {   // MODE 2: projection epilogue
    const float* bq = dir ? bq1 : bq0;
    const float* bk = dir ? bk1 : bk0;
    const float* bv = dir ? bv1 : bv0;
    u8* k8p = K8 + (long)dir * 2048 * 4096;
    u8* v8p = V8 + (long)dir * 8 * 512 * 2048;
#pragma unroll
    for (int i = 0; i < 4; ++i) {
      const int row0 = m0 + wm + i * 16 + q * 4;
#pragma unroll
      for (int j = 0; j < 4; ++j) {
        const int colg = n0 + wn + j * 16 + r16;
        if (n0 < 4096) {
          float bvv = bq[colg];
#pragma unroll
          for (int r = 0; r < 4; ++r)
            C8[(long)(row0 + r) * 4096 + colg] = to_fp8(acc[i][j][r] + bvv);
        } else if (n0 < 8192) {
          int kc = colg - 4096;
          float bvv = bk[kc];
#pragma unroll
          for (int r = 0; r < 4; ++r)
            k8p[(long)(row0 + r) * 4096 + kc] = to_fp8(acc[i][j][r] + bvv);
        } else {
          int vcol = colg - 8192;
          float bvv = bv[vcol];
          int w = __builtin_amdgcn_cvt_pk_fp8_f32(acc[i][j][0] + bvv, acc[i][j][1] + bvv, 0, false);
          w = __builtin_amdgcn_cvt_pk_fp8_f32(acc[i][j][2] + bvv, acc[i][j][3] + bvv, w, true);
          *(int*)(v8p + (long)vcol * 2048 + row0) = w;   // 4 rows of V^T col
        }
      }
    }
  }
}

// ---------------- bf16 split-K output linear, both dirs batched -------------
// z: dir=z>>3, sp=z&7. C[z] (f32) = res[dir][:, sp*Ks:] @ wl[dir][:, sp*Ks:]^T
__global__ __launch_bounds__(256, 2) void gemm_splitk(
    const bf16_t* __restrict__ A, int lda, long aDir,
    const bf16_t* __restrict__ B, int ldb, long bDir,
    float* __restrict__ C, int ldc, long zC, int Ks)
{
  __shared__ __align__(16) bf16_t lds_a[128 * 64];
  __shared__ __align__(16) bf16_t lds_b[128 * 64];

  const int tid = threadIdx.x;
  const int lane = tid & 63;
  const int wid = tid >> 6;
  const int wm = (wid >> 1) * 64;
  const int wn = (wid & 1) * 64;
  const int m0 = blockIdx.y * 128;
  const int n0 = blockIdx.x * 128;
  const int z = blockIdx.z;
  const int dir = z >> 3, sp = z & 7;
  A += (long)dir * aDir + (long)sp * Ks;
  B += (long)dir * bDir + (long)sp * Ks;
  C += (long)z * zC;

  const bf16_t* gA[4];
  const bf16_t* gB[4];
  int ldsOff[4];
#pragma unroll
  for (int j = 0; j < 4; ++j) {
    int p = j * 256 + tid;
    int row = p >> 3;
    int ksl = (p & 7) ^ (row & 7);
    ldsOff[j] = p * 8;
    gA[j] = A + (long)(m0 + row) * lda + ksl * 8;
    gB[j] = B + (long)(n0 + row) * ldb + ksl * 8;
  }

  f32x4 acc[4][4];
#pragma unroll
  for (int i = 0; i < 4; ++i)
#pragma unroll
    for (int j = 0; j < 4; ++j) acc[i][j] = f32x4{0.f, 0.f, 0.f, 0.f};

  const int q = lane >> 4;
  const int r16 = lane & 15;

  for (int kt = 0; kt < Ks; kt += 64) {
#pragma unroll
    for (int j = 0; j < 4; ++j) {
      async_copy16(gA[j] + kt, &lds_a[ldsOff[j]]);
      async_copy16(gB[j] + kt, &lds_b[ldsOff[j]]);
    }
    __syncthreads();
#pragma unroll
    for (int s = 0; s < 2; ++s) {
      bf16x8 af[4], bfr[4];
#pragma unroll
      for (int i = 0; i < 4; ++i) {
        int ra = wm + i * 16 + r16;
        int ka = ((s * 4 + q) ^ (ra & 7)) * 8;
        af[i] = *(const bf16x8*)&lds_a[ra * 64 + ka];
        int rb = wn + i * 16 + r16;
        int kb = ((s * 4 + q) ^ (rb & 7)) * 8;
        bfr[i] = *(const bf16x8*)&lds_b[rb * 64 + kb];
      }
#pragma unroll
      for (int i = 0; i < 4; ++i)
#pragma unroll
        for (int j = 0; j < 4; ++j)
          acc[i][j] = __builtin_amdgcn_mfma_f32_16x16x32_bf16(af[i], bfr[j], acc[i][j], 0, 0, 0);
    }
    __syncthreads();
  }

#pragma unroll
  for (int i = 0; i < 4; ++i) {
    const int row0 = m0 + wm + i * 16 + q * 4;
#pragma unroll
    for (int j = 0; j < 4; ++j) {
      const int colg = n0 + wn + j * 16 + r16;
#pragma unroll
      for (int r = 0; r < 4; ++r)
        C[(long)(row0 + r) * ldc + colg] = acc[i][j][r];
    }
  }
}

// out[row][dir*512+col] = sum_s spart[dir][s][row][col] + bias[col] + resid[row][col]
__global__ __launch_bounds__(256) void reduce_splitk(
    const float* __restrict__ spart,
    const float* __restrict__ b0, const float* __restrict__ b1,
    const float* __restrict__ r0, const float* __restrict__ r1,
    float* __restrict__ out) {
  const int dir = blockIdx.y;
  const float* part = spart + (long)dir * 8 * 2048 * 512;
  const float* bias = dir ? b1 : b0;
  const float* resid = dir ? r1 : r0;
  int i = blockIdx.x * 256 + threadIdx.x;
  int row = i >> 7;
  int col = (i & 127) * 4;
  float4 a = *(const float4*)(resid + (long)row * 512 + col);
  float4 b = *(const float4*)(bias + col);
  a.x += b.x; a.y += b.y; a.z += b.z; a.w += b.w;
  for (int s = 0; s < 8; ++s) {
    float4 p = *(const float4*)(part + (long)s * 2048 * 512 + (long)row * 512 + col);
    a.x += p.x; a.y += p.y; a.z += p.z; a.w += p.w;
  }
  *(float4*)(out + (long)row * 1024 + dir * 512 + col) = a;
}

extern "C" void kernel_launch(void* const* d_in, const int* in_sizes, int n_in,
                              void* d_out, int out_size, void* d_ws, size_t ws_size,
                              hipStream_t stream)
{
  (void)in_sizes; (void)n_in; (void)out_size; (void)ws_size;
  const int N = 2048, D = 512, HD = 4096;
  const int NW = HD * D;                       // 2,097,152

  const float* img_f  = (const float*)d_in[0];
  const float* meta_f = (const float*)d_in[1];
  float* out = (float*)d_out;

  // scratch: 168 MB (ws ~= 268 MB per R6 fill counter)
  char* pp = (char*)d_ws;
  u8*     img8  = (u8*)pp;     pp += (size_t)N * D;            // 1 MB
  u8*     meta8 = (u8*)pp;     pp += (size_t)N * D;
  u8*     w8    = (u8*)pp;     pp += (size_t)2 * 3 * NW;       // 12 MB [dir][q,k,v]
  bf16_t* wl16  = (bf16_t*)pp; pp += (size_t)2 * NW * 2;       // 8 MB
  u8*     q8    = (u8*)pp;     pp += (size_t)2 * N * HD;       // 16 MB
  u8*     k8    = (u8*)pp;     pp += (size_t)2 * N * HD;       // 16 MB
  u8*     vt8   = (u8*)pp;     pp += (size_t)2 * N * HD;       // 16 MB [dir][8][512][2048]
  bf16_t* res   = (bf16_t*)pp; pp += (size_t)2 * N * HD * 2;   // 32 MB
  u8*     S8    = (u8*)pp;     pp += (size_t)2 * 8 * N * N;    // 64 MB [dir][8][N][N]
  float*  partial = (float*)pp; pp += (size_t)2 * 8 * 16 * 2048 * 4;  // 2 MB
  float*  spart = (float*)S8;  // 64 MB f32 aliases S8; safe: PV reads S8 before splitK writes

  const float rs = 1.f / sqrtf((float)D);
  dim3 blk(256);

  // cast X + the 6 QKV weights to fp8 (dir0: Wq_m,Wk_i,Wv_i; dir1: Wq_i,Wk_m,Wv_m)
  CastArgs ca;
  ca.s[0] = img_f;                    ca.d[0] = img8;          ca.n[0] = N * D;
  ca.s[1] = meta_f;                   ca.d[1] = meta8;         ca.n[1] = N * D;
  ca.s[2] = (const float*)d_in[2];    ca.d[2] = w8;            ca.n[2] = NW;
  ca.s[3] = (const float*)d_in[4];    ca.d[3] = w8 + (size_t)NW;     ca.n[3] = NW;
  ca.s[4] = (const float*)d_in[6];    ca.d[4] = w8 + (size_t)2 * NW; ca.n[4] = NW;
  ca.s[5] = (const float*)d_in[8];    ca.d[5] = w8 + (size_t)3 * NW; ca.n[5] = NW;
  ca.s[6] = (const float*)d_in[10];   ca.d[6] = w8 + (size_t)4 * NW; ca.n[6] = NW;
  ca.s[7] = (const float*)d_in[12];   ca.d[7] = w8 + (size_t)5 * NW; ca.n[7] = NW;
  cast_f32_fp8_8<<<dim3(NW / 2048, 8), blk, 0, stream>>>(ca);

  // output-linear weights -> bf16
  cast_f32_bf16_2<<<dim3(NW / 1024, 2), blk, 0, stream>>>(
      (const float*)d_in[14], (const float*)d_in[16], wl16, wl16 + NW, NW);

  // merged projections, both dirs: [Xq|Xkv] @ [Wq;Wk;Wv]^T -> q8/k8/vt8
  gemm_f8<2><<<dim3(96, 16, 2), blk, 0, stream>>>(
      img8, meta8, D, 0, 0,
      w8, D, (long)3 * NW, 0,
      q8, HD, (long)N * HD, 0,
      k8, vt8, nullptr,
      (const float*)d_in[3], (const float*)d_in[5], (const float*)d_in[7],
      (const float*)d_in[9], (const float*)d_in[11], (const float*)d_in[13],
      1.f, D);

  // QK, both dirs x 8 heads: S8 = fp8(exp(QK^T/sqrt(512))) + rowsum partials
  gemm_f8<0><<<dim3(16, 16, 16), blk, 0, stream>>>(
      q8, nullptr, HD, (long)N * HD, D,
      k8, HD, (long)N * HD, D,
      S8, N, (long)8 * N * N, (long)N * N,
      nullptr, nullptr, partial,
      nullptr, nullptr, nullptr, nullptr, nullptr, nullptr,
      rs, D);

  // PV: res = (S8 @ V) / rowsum
  gemm_f8<1><<<dim3(4, 16, 16), blk, 0, stream>>>(
      S8, nullptr, N, (long)8 * N * N, (long)N * N,
      vt8, N, (long)8 * D * N, (long)D * N,
      res, HD, (long)N * HD, D,
      nullptr, nullptr, partial,
      nullptr, nullptr, nullptr, nullptr, nullptr, nullptr,
      1.f, N);

  // output linear, split-K, both dirs (bf16 -> f32 partials in spart)
  gemm_splitk<<<dim3(4, 16, 16), blk, 0, stream>>>(
      res, HD, (long)N * HD,
      wl16, HD, (long)NW,
      spart, D, (long)N * D, D);

  reduce_splitk<<<dim3(1024, 2), blk, 0, stream>>>(
      spart, (const float*)d_in[15], (const float*)d_in[17],
      img_f, meta_f, out);
}